// Round 8
// baseline (169.219 us; speedup 1.0000x reference)
//
#include <hip/hip_runtime.h>
#include <math.h>

#define NN 131072
#define KK 27
#define FIN 3
#define FOUT 32
#define EPS 1e-5f

typedef _Float16 f16;
typedef __attribute__((ext_vector_type(8))) _Float16 f16x8;
typedef __attribute__((ext_vector_type(4)))  float   f32x4;
typedef __attribute__((ext_vector_type(16))) float   f32x16;

// ---------------------------------------------------------------------------
// Pack one spatial tap k of w2 (f32 [32][32]) into f16 MFMA B-fragments:
// w2p[k][half][lane][j]; B layout for v_mfma_f32_32x32x16:
// col = lane&31, kdim = (lane>>5)*8 + j.  (proven since round 1)
// ---------------------------------------------------------------------------
__device__ __forceinline__ void pack_w2_block(
    const float* __restrict__ w2, f16* __restrict__ w2p, int k, int t)
{
#pragma unroll
    for (int r = 0; r < 4; ++r) {
        const int e    = r * 256 + t;
        const int half = e >> 9;
        const int l    = (e >> 3) & 63;
        const int j    = e & 7;
        const int krow = half * 16 + ((l >> 5) << 3) + j;
        const int n    = l & 31;
        w2p[k * 1024 + e] = (f16)w2[k * (FOUT * FOUT) + krow * FOUT + n];
    }
}

// ---------------------------------------------------------------------------
// Dispatch 1: conv1 + w2 pack (tail blocks).
// h = silu(bn1(einsum(x_feats[nbr_idx], w1))) -> [N,32] f16
// NEW: asm-forced gather window. 2 chunks x 7 taps in flight (42 VGPR,
// up to 42 scattered dword loads outstanding) consumed under counted
// s_waitcnt vmcnt(N) + sched_barrier(0). launch_bounds(256,2) gives the
// allocator a 256-VGPR budget so it cannot shuffle pending-load dests
// through AGPRs (round-7 lesson: VGPR=80 proved the window was destroyed).
// ---------------------------------------------------------------------------
__global__ __launch_bounds__(256, 2) void conv1_pack_kernel(
    const float* __restrict__ x_feats,   // [N,3]
    const int*   __restrict__ nbr_idx,   // [N,27]
    const float* __restrict__ w1,        // [27,3,32]
    const float* __restrict__ g1,  const float* __restrict__ b1,
    const float* __restrict__ m1,  const float* __restrict__ v1,
    f16* __restrict__ h_out,             // [N,32] f16
    const float* __restrict__ w2, f16* __restrict__ w2p)
{
    if (blockIdx.x >= NN / 256) {        // tail blocks: pack w2 tap
        pack_w2_block(w2, w2p, blockIdx.x - NN / 256, threadIdx.x);
        return;
    }
    const int n = blockIdx.x * 256 + threadIdx.x;

    int idxs[KK];
    const int* nb = nbr_idx + (size_t)n * KK;
#pragma unroll
    for (int k = 0; k < KK; ++k) idxs[k] = nb[k];
#pragma unroll
    for (int k = 0; k < KK; ++k) asm volatile("" : "+v"(idxs[k]));

    float acc[FOUT];
#pragma unroll
    for (int o = 0; o < FOUT; ++o) acc[o] = 0.f;

    float xw[14][3];                     // 14-tap rolling window (42 VGPR)

#define C1_ISSUE(tap, s) do {                                                \
        const float* p_ = x_feats + (size_t)idxs[tap] * FIN;                 \
        asm volatile("global_load_dword %0, %1, off"                         \
                     : "=v"(xw[s][0]) : "v"(p_));                            \
        asm volatile("global_load_dword %0, %1, off offset:4"                \
                     : "=v"(xw[s][1]) : "v"(p_));                            \
        asm volatile("global_load_dword %0, %1, off offset:8"                \
                     : "=v"(xw[s][2]) : "v"(p_));                            \
    } while (0)

#pragma unroll
    for (int t = 0; t < 7; ++t) C1_ISSUE(t, t);      // prologue: chunk 0

    // chunks of {7,7,7,6} taps; issue chunk c+1, consume chunk c.
#pragma unroll
    for (int c = 0; c < 4; ++c) {
        const int cs  = (c < 3) ? 7 : 6;             // this chunk's taps
        if (c + 1 < 4) {                             // issue next chunk
            const int ns = (c + 1 < 3) ? 7 : 6;
#pragma unroll
            for (int q = 0; q < 7; ++q)
                if (q < ns) C1_ISSUE((c + 1) * 7 + q, ((c + 1) * 7 + q) % 14);
        }
        // outstanding after issue = this(21|18) + next(21|18); need this done
        if      (c == 0) asm volatile("s_waitcnt vmcnt(21)");
        else if (c == 1) asm volatile("s_waitcnt vmcnt(21)");
        else if (c == 2) asm volatile("s_waitcnt vmcnt(18)");
        else             asm volatile("s_waitcnt vmcnt(0)");
        __builtin_amdgcn_sched_barrier(0);           // rule #18

#pragma unroll
        for (int q = 0; q < 7; ++q) {
            if (q < cs) {
                const int tap = c * 7 + q;
                const int s   = tap % 14;
                const float* w = w1 + tap * (FIN * FOUT);   // uniform s_load
#pragma unroll
                for (int o = 0; o < FOUT; ++o) {
                    float a = acc[o];
                    a = fmaf(xw[s][0], w[o],            a);
                    a = fmaf(xw[s][1], w[FOUT + o],     a);
                    a = fmaf(xw[s][2], w[2 * FOUT + o], a);
                    acc[o] = a;
                }
            }
        }
    }
#undef C1_ISSUE

    f16* hr = h_out + (size_t)n * FOUT;
#pragma unroll
    for (int g = 0; g < 4; ++g) {
        f16x8 hv;
#pragma unroll
        for (int j = 0; j < 8; ++j) {
            const int o = g * 8 + j;
            const float sc = g1[o] * rsqrtf(v1[o] + EPS);
            float v = (acc[o] - m1[o]) * sc + b1[o];
            v = v / (1.f + __expf(-v));              // silu
            hv[j] = (f16)v;
        }
        *(f16x8*)(hr + g * 8) = hv;                  // 16B stores
    }
}

// ---------------------------------------------------------------------------
// Dispatch 2 (MFMA): x_out = einsum(h[nbr_idx], w2) + fused point branch.
// Round-7 asm window retained, but with launch_bounds(256,2) so the 96-VGPR
// 6-slot window can actually live in arch VGPRs (round-7 VGPR=80 proved the
// allocator destroyed it under the default occupancy heuristic). Loads use
// offset-immediates (a2 = +32B, b2 = +1024B) to halve address VALU work.
// Counted vmcnt(20..0), sched_barrier after each wait, setprio around MFMA.
// ---------------------------------------------------------------------------
__global__ __launch_bounds__(256, 2) void conv2_mfma_kernel(
    const f16*   __restrict__ h,         // [N,32] f16
    const int*   __restrict__ nbr_idx,   // [N,27]
    const f16*   __restrict__ w2p,       // packed [27][2][64][8] f16
    const float* __restrict__ z_feats,   // [N,3]
    const float* __restrict__ mlp_w,     // [3,32]
    const float* __restrict__ mlp_b,
    const float* __restrict__ mg, const float* __restrict__ mbe,
    const float* __restrict__ mm, const float* __restrict__ mv,
    float* __restrict__ out)             // [2,N,32]
{
    const int lane = threadIdx.x & 63;
    const int wave = threadIdx.x >> 6;
    const int base = (blockIdx.x * 4 + wave) * 32;   // this wave's node base
    const int row  = lane & 31;                      // A row
    const int hi   = lane >> 5;                      // contraction half of 8

    int idxs[KK];
    const int* nb = nbr_idx + (size_t)(base + row) * KK;
#pragma unroll
    for (int k = 0; k < KK; ++k) idxs[k] = nb[k];
#pragma unroll
    for (int k = 0; k < KK; ++k) asm volatile("" : "+v"(idxs[k]));

    f32x16 acc0 = {};                                // feats [0,16) partial
    f32x16 acc1 = {};                                // feats [16,32) partial

    f32x4 wa1[6], wa2[6], wb1[6], wb2[6];            // 6-slot rolling window

#define C2_ISSUE(t, s) do {                                                  \
        const f16* hr_ = h + (size_t)idxs[t] * FOUT + hi * 8;                \
        const f16* bb_ = w2p + (t) * 1024 + lane * 8;                        \
        asm volatile("global_load_dwordx4 %0, %1, off"                       \
                     : "=v"(wa1[s]) : "v"(hr_));                             \
        asm volatile("global_load_dwordx4 %0, %1, off offset:32"             \
                     : "=v"(wa2[s]) : "v"(hr_));                             \
        asm volatile("global_load_dwordx4 %0, %1, off"                       \
                     : "=v"(wb1[s]) : "v"(bb_));                             \
        asm volatile("global_load_dwordx4 %0, %1, off offset:1024"           \
                     : "=v"(wb2[s]) : "v"(bb_));                             \
    } while (0)

#pragma unroll
    for (int t = 0; t < 6; ++t) C2_ISSUE(t, t);      // prologue: 24 in flight

#pragma unroll
    for (int k = 0; k < KK; ++k) {                   // fully unrolled: k const
        const int rem = KK - 1 - k;                  // taps issued after k
        if      (rem >= 5) asm volatile("s_waitcnt vmcnt(20)");
        else if (rem == 4) asm volatile("s_waitcnt vmcnt(16)");
        else if (rem == 3) asm volatile("s_waitcnt vmcnt(12)");
        else if (rem == 2) asm volatile("s_waitcnt vmcnt(8)");
        else if (rem == 1) asm volatile("s_waitcnt vmcnt(4)");
        else               asm volatile("s_waitcnt vmcnt(0)");
        __builtin_amdgcn_sched_barrier(0);           // rule #18: pin the wait

        const int s = k % 6;
        const f16x8 a1 = __builtin_bit_cast(f16x8, wa1[s]);
        const f16x8 a2 = __builtin_bit_cast(f16x8, wa2[s]);
        const f16x8 b1 = __builtin_bit_cast(f16x8, wb1[s]);
        const f16x8 b2 = __builtin_bit_cast(f16x8, wb2[s]);
        __builtin_amdgcn_s_setprio(1);
        acc0 = __builtin_amdgcn_mfma_f32_32x32x16_f16(a1, b1, acc0, 0, 0, 0);
        acc1 = __builtin_amdgcn_mfma_f32_32x32x16_f16(a2, b2, acc1, 0, 0, 0);
        __builtin_amdgcn_s_setprio(0);

        if (k + 6 < KK) C2_ISSUE(k + 6, s);          // refill freed slot
    }
#undef C2_ISSUE

    // ---- epilogue: point branch for output column n0, fused add + store ----
    const int n0 = lane & 31;
    const float wc0 = mlp_w[n0];
    const float wc1 = mlp_w[FOUT + n0];
    const float wc2 = mlp_w[2 * FOUT + n0];
    const float sc  = mg[n0] * rsqrtf(mv[n0] + EPS);
    const float bi  = mlp_b[n0];
    const float mmv = mm[n0];
    const float mbv = mbe[n0];

#pragma unroll
    for (int r = 0; r < 16; ++r) {
        const int m    = (r & 3) + ((r >> 2) << 3) + (hi << 2); // C/D row map
        const int node = base + m;
        const float* zr = z_feats + (size_t)node * FIN;
        float z = bi;
        z = fmaf(zr[0], wc0, z);
        z = fmaf(zr[1], wc1, z);
        z = fmaf(zr[2], wc2, z);
        z = (z - mmv) * sc + mbv;
        z = fmaxf(z, 0.f);
        const float v = acc0[r] + acc1[r] + z;
        out[(size_t)node * FOUT + n0] = v;
        out[(size_t)NN * FOUT + (size_t)node * FOUT + n0] = v;
    }
}

extern "C" void kernel_launch(void* const* d_in, const int* in_sizes, int n_in,
                              void* d_out, int out_size, void* d_ws, size_t ws_size,
                              hipStream_t stream) {
    const float* x_feats = (const float*)d_in[0];
    const float* z_feats = (const float*)d_in[1];
    const int*   nbr_idx = (const int*)d_in[2];
    const float* w1      = (const float*)d_in[3];
    const float* bn1_g   = (const float*)d_in[4];
    const float* bn1_b   = (const float*)d_in[5];
    const float* bn1_m   = (const float*)d_in[6];
    const float* bn1_v   = (const float*)d_in[7];
    const float* w2      = (const float*)d_in[8];
    const float* mlp_w   = (const float*)d_in[9];
    const float* mlp_b   = (const float*)d_in[10];
    const float* mlp_g   = (const float*)d_in[11];
    const float* mlp_be  = (const float*)d_in[12];
    const float* mlp_m   = (const float*)d_in[13];
    const float* mlp_v   = (const float*)d_in[14];

    // workspace: h [0, 8M)   w2p [8M, 8M+55296)
    f16* h   = (f16*)d_ws;
    f16* w2p = (f16*)((char*)d_ws + (size_t)8 * 1024 * 1024);
    float* out = (float*)d_out;

    conv1_pack_kernel<<<NN / 256 + KK, 256, 0, stream>>>(
        x_feats, nbr_idx, w1, bn1_g, bn1_b, bn1_m, bn1_v, h, w2, w2p);
    conv2_mfma_kernel<<<NN / 128, 256, 0, stream>>>(
        h, nbr_idx, w2p, z_feats, mlp_w, mlp_b, mlp_g, mlp_be,
        mlp_m, mlp_v, out);
}